// Round 5
// baseline (1668.531 us; speedup 1.0000x reference)
//
#include <hip/hip_runtime.h>
#include <math.h>

#define N 4096
#define DIM 64
#define MAX_ITER 50
#define EPS 0.1f
#define INV_EPS 10.0f
#define THRESH 0.1f

// 512 blocks x 1024 threads (16 waves). 2 waves per row, 8 rows/block.
// launch_bounds(1024,8) -> 8 waves/EU -> VGPR<=64 -> 2 blocks/CU; grid == exact
// capacity (512 = 2x256 CUs) so all blocks co-resident -> barrier cannot deadlock.
#define NBLK 512
#define TPB 1024
#define WAVES 16
#define RPB 8    // rows per block
#define NREP 16  // wake replicas

// ws layout (floats). All cross-block data accessed ONLY via relaxed
// agent-scope atomics (L2-bypass, coherent at L3, no cache-wide inv/wb ops
// -> C/Ct stay L2-resident across phases).
#define WS_U 0
#define WS_V N
#define WS_FLAGS (2 * N)                  // 512 x (u32 gen, f32 val) 8B pairs
#define WS_GGEN (2 * N + 2 * NBLK)        // 16 replicas x 16-word stride
#define WS_TOTAL (2 * N + 2 * NBLK + NREP * 16)

// ---------------- init: zero u, v, flags, replicas ----------------
__global__ void init_ws(float* __restrict__ ws) {
    int i = blockIdx.x * 256 + threadIdx.x;
    if (i < WS_TOTAL) ws[i] = 0.0f;
}

// ---------------- build D[i][j] = sum_d (A[i][d]-B[j][d])^2 ----------------
__global__ __launch_bounds__(256) void build_dist(const float* __restrict__ A,
                                                  const float* __restrict__ B,
                                                  float* __restrict__ Dst) {
    __shared__ float As[64][68];
    __shared__ float Bs[64][68];
    const int i0 = blockIdx.y << 6, j0 = blockIdx.x << 6;
    const int t = threadIdx.x;
    const float* Ag = A + (size_t)i0 * DIM;
    const float* Bg = B + (size_t)j0 * DIM;
    for (int k = t; k < 4096; k += 256) {
        As[k >> 6][k & 63] = Ag[k];
        Bs[k >> 6][k & 63] = Bg[k];
    }
    __syncthreads();
    const int ty = t >> 4, tx = t & 15;
    float acc[4][4] = {{0.f}};
    for (int d = 0; d < DIM; d += 4) {
        float4 av[4], bv[4];
#pragma unroll
        for (int a = 0; a < 4; ++a) av[a] = *(const float4*)&As[ty + 16 * a][d];
#pragma unroll
        for (int b = 0; b < 4; ++b) bv[b] = *(const float4*)&Bs[tx + 16 * b][d];
#pragma unroll
        for (int a = 0; a < 4; ++a)
#pragma unroll
            for (int b = 0; b < 4; ++b) {
                float d0 = av[a].x - bv[b].x;
                float d1 = av[a].y - bv[b].y;
                float d2 = av[a].z - bv[b].z;
                float d3 = av[a].w - bv[b].w;
                acc[a][b] = fmaf(d0, d0, acc[a][b]);
                acc[a][b] = fmaf(d1, d1, acc[a][b]);
                acc[a][b] = fmaf(d2, d2, acc[a][b]);
                acc[a][b] = fmaf(d3, d3, acc[a][b]);
            }
    }
#pragma unroll
    for (int a = 0; a < 4; ++a) {
        int i = i0 + ty + 16 * a;
        float* drow = Dst + (size_t)i * N + j0;
#pragma unroll
        for (int b = 0; b < 4; ++b) drow[tx + 16 * b] = acc[a][b];
    }
}

// -------- grid barrier: flag-array + dedicated scanner, payload-carrying -----
// Arrive: one 8B relaxed-agent store (gen, blockPartial) per block. Block 0
// wave 0 scans all 512 flags (8 loads/lane), reduces payload, publishes
// (gen,sum) to 16 replicas. Others poll their replica. Ordering: the entry
// __syncthreads drains every lane's stores before the flag store.
__device__ __forceinline__ float grid_sync(float* ws, int b, int t, unsigned G,
                                           const float* red2, float* bcast,
                                           bool wake) {
    __syncthreads();  // red2 complete; all prior stores retired
    if (t == 0) {
        float s = 0.f;
#pragma unroll
        for (int i = 0; i < WAVES; ++i) s += red2[i];
        unsigned long long pk = (unsigned long long)G |
                                ((unsigned long long)__float_as_uint(s) << 32);
        __hip_atomic_store((unsigned long long*)(ws + WS_FLAGS) + b, pk,
                           __ATOMIC_RELAXED, __HIP_MEMORY_SCOPE_AGENT);
    }
    if (b == 0 && t < 64) {  // scanner wave
        unsigned long long* fl = (unsigned long long*)(ws + WS_FLAGS);
        float sum;
        for (;;) {
            bool ok = true;
            sum = 0.f;
#pragma unroll
            for (int j = 0; j < NBLK / 64; ++j) {
                unsigned long long q =
                    __hip_atomic_load(fl + (t * (NBLK / 64) + j),
                                      __ATOMIC_RELAXED, __HIP_MEMORY_SCOPE_AGENT);
                ok = ok && ((unsigned)q >= G);
                sum += __uint_as_float((unsigned)(q >> 32));
            }
            if (__all(ok)) break;
            __builtin_amdgcn_s_sleep(1);
        }
#pragma unroll
        for (int off = 32; off; off >>= 1) sum += __shfl_xor(sum, off);
        if (wake && t < NREP) {
            unsigned long long pk =
                (unsigned long long)G |
                ((unsigned long long)__float_as_uint(sum) << 32);
            __hip_atomic_store((unsigned long long*)(ws + WS_GGEN) + t * 8, pk,
                               __ATOMIC_RELAXED, __HIP_MEMORY_SCOPE_AGENT);
        }
        if (t == 0) *bcast = sum;
    } else if (t == 0 && wake) {  // b != 0
        unsigned long long* gp =
            (unsigned long long*)(ws + WS_GGEN) + (b & (NREP - 1)) * 8;
        unsigned long long q;
        for (;;) {
            q = __hip_atomic_load(gp, __ATOMIC_RELAXED, __HIP_MEMORY_SCOPE_AGENT);
            if ((unsigned)q >= G) break;
            __builtin_amdgcn_s_sleep(2);
        }
        *bcast = __uint_as_float((unsigned)(q >> 32));
    }
    __syncthreads();
    return *bcast;  // valid when wake (all blocks) or b==0
}

// ------- stage a 4096-float vector into LDS, PRE-SCALED by INV_EPS -----------
// Working in exponent units turns per-element {sub,sub,mul} into {fma,sub}.
__device__ __forceinline__ void stage(const float* __restrict__ src,
                                      float* __restrict__ sv, int t) {
    const unsigned long long* s8 = (const unsigned long long*)src;
#pragma unroll
    for (int i = 0; i < 2; ++i) {
        int idx = t + TPB * i;  // 0..2047
        unsigned long long q = __hip_atomic_load(s8 + idx, __ATOMIC_RELAXED,
                                                 __HIP_MEMORY_SCOPE_AGENT);
        sv[2 * idx] = __uint_as_float((unsigned)q) * INV_EPS;
        sv[2 * idx + 1] = __uint_as_float((unsigned)(q >> 32)) * INV_EPS;
    }
}

// ------- one Sinkhorn half-step, 2 waves per row, single-pass online LSE -----
// Scaled domain: d' = (v_j - C_ij)*INV_EPS computed as fma(C, -INV_EPS, v').
// Each wave covers 32 columns/lane; waves of a row merge (m,s) through LDS.
template <bool WERR>
__device__ __forceinline__ void phase(const float* __restrict__ Mtx,
                                      const float* __restrict__ sv,
                                      float* __restrict__ dst, int row,
                                      int lane, int wv, int half, float target,
                                      float* red2, float* sm, float* ss) {
    const float4* __restrict__ rowp = (const float4*)(Mtx + (size_t)row * N);
    const float4* __restrict__ svv = (const float4*)sv;
    float old = 0.f;
    if (WERR && half == 0 && lane == 0)  // hoisted; overlaps streaming loop
        old = __hip_atomic_load(&dst[row], __ATOMIC_RELAXED,
                                __HIP_MEMORY_SCOPE_AGENT);
    float m = -3.0e38f, s = 0.f;
#pragma unroll
    for (int g = 0; g < 2; ++g) {
        float4 c[4], w[4];
#pragma unroll
        for (int k = 0; k < 4; ++k) {
            const int f = lane + 64 * (8 * half + 4 * g + k);
            c[k] = rowp[f];
            w[k] = svv[f];
        }
        float d[16];
#pragma unroll
        for (int k = 0; k < 4; ++k) {
            d[4 * k + 0] = fmaf(c[k].x, -INV_EPS, w[k].x);
            d[4 * k + 1] = fmaf(c[k].y, -INV_EPS, w[k].y);
            d[4 * k + 2] = fmaf(c[k].z, -INV_EPS, w[k].z);
            d[4 * k + 3] = fmaf(c[k].w, -INV_EPS, w[k].w);
        }
        float m4[4];
#pragma unroll
        for (int k = 0; k < 4; ++k)
            m4[k] = fmaxf(fmaxf(d[4 * k], d[4 * k + 1]),
                          fmaxf(d[4 * k + 2], d[4 * k + 3]));
        float mg = fmaxf(fmaxf(m4[0], m4[1]), fmaxf(m4[2], m4[3]));
        float mn = fmaxf(m, mg);
        float ps = 0.f;
#pragma unroll
        for (int k = 0; k < 16; ++k) ps += __expf(d[k] - mn);
        s = fmaf(s, __expf(m - mn), ps);
        m = mn;
    }
#pragma unroll
    for (int off = 32; off; off >>= 1) {
        float mo = __shfl_xor(m, off);
        float so = __shfl_xor(s, off);
        float mn = fmaxf(m, mo);
        s = fmaf(s, __expf(m - mn), so * __expf(mo - mn));
        m = mn;
    }
    if (lane == 0) {
        sm[wv] = m;
        ss[wv] = s;
    }
    __syncthreads();
    if (lane == 0) {
        float e = 0.f;
        if (half == 0) {
            float mo = sm[wv + 8], so = ss[wv + 8];
            float mn = fmaxf(m, mo);
            s = fmaf(s, __expf(m - mn), so * __expf(mo - mn));
            m = mn;
            // un = target - EPS*(m' + log s)   (m' is in exponent units)
            float un = fmaf(-EPS, m + __logf(s), target);
            if (WERR) e = fabsf(un - old);
            __hip_atomic_store(&dst[row], un, __ATOMIC_RELAXED,
                               __HIP_MEMORY_SCOPE_AGENT);
        }
        red2[wv] = e;
    }
}

// ---------------- persistent kernel: all iterations + final ----------------
__global__ __launch_bounds__(TPB, 8) void sinkhorn_persist(
    const float* __restrict__ Cm, const float* __restrict__ Ct,
    float* __restrict__ ws, float* __restrict__ out, float target) {
    __shared__ float sv[N];  // 16 KB staged (scaled) vector
    __shared__ float red2[WAVES];
    __shared__ float sm[WAVES], ss[WAVES];
    __shared__ float bcast;
    float* u = ws + WS_U;
    float* v = ws + WS_V;
    const int t = threadIdx.x;
    const int b = blockIdx.x;
    const int lane = t & 63, wv = t >> 6;
    const int half = wv >> 3;            // 0 or 1: which half of the row
    const int row = (b << 3) + (wv & 7); // this wave's row
    unsigned G = 1;
    float errv = 1e30f;

    for (int it = 0; it < MAX_ITER; ++it) {
        stage(v, sv, t);
        __syncthreads();
        phase<true>(Cm, sv, u, row, lane, wv, half, target, red2, sm, ss);
        errv = grid_sync(ws, b, t, G++, red2, &bcast, true);  // total err
        stage(u, sv, t);
        __syncthreads();
        phase<false>(Ct, sv, v, row, lane, wv, half, target, red2, sm, ss);
        grid_sync(ws, b, t, G++, red2, &bcast, true);
        // reference latches done AFTER applying this iteration's updates.
        if (errv < THRESH) break;  // uniform: same published value everywhere
    }

    // ---- final: pi = exp((u_i + v_j - C_ij)/eps), cost = sum(pi*C) ----
    // Ct (aliasing out[0..N^2)) is dead from here; pi writes may clobber it.
    stage(v, sv, t);  // scaled v
    __syncthreads();
    {
        float* pi = out + 1;
        float ui = 0.f;
        if (lane == 0)
            ui = __hip_atomic_load(&u[row], __ATOMIC_RELAXED,
                                   __HIP_MEMORY_SCOPE_AGENT);
        ui = __shfl(ui, 0) * INV_EPS;  // exponent units
        const float4* __restrict__ crow = (const float4*)(Cm + (size_t)row * N);
        float4* __restrict__ prow = (float4*)(pi + (size_t)row * N);
        const float4* __restrict__ svv = (const float4*)sv;
        float csum = 0.f;
#pragma unroll
        for (int k = 0; k < 8; ++k) {
            const int f = lane + 64 * (8 * half + k);
            float4 c = crow[f];
            float4 w = svv[f];
            float4 p;
            p.x = __expf(fmaf(c.x, -INV_EPS, ui + w.x));
            p.y = __expf(fmaf(c.y, -INV_EPS, ui + w.y));
            p.z = __expf(fmaf(c.z, -INV_EPS, ui + w.z));
            p.w = __expf(fmaf(c.w, -INV_EPS, ui + w.w));
            prow[f] = p;
            csum = fmaf(p.x, c.x, csum);
            csum = fmaf(p.y, c.y, csum);
            csum = fmaf(p.z, c.z, csum);
            csum = fmaf(p.w, c.w, csum);
        }
#pragma unroll
        for (int off = 32; off; off >>= 1) csum += __shfl_xor(csum, off);
        if (lane == 0) red2[wv] = csum;
    }
    // cost rides the final barrier payload; only the scanner needs the total.
    float ctot = grid_sync(ws, b, t, G++, red2, &bcast, false);
    if (b == 0 && t == 0) out[0] = ctot;
}

extern "C" void kernel_launch(void* const* d_in, const int* in_sizes, int n_in,
                              void* d_out, int out_size, void* d_ws, size_t ws_size,
                              hipStream_t stream) {
    const float* x = (const float*)d_in[0];  // [4096,64]
    const float* y = (const float*)d_in[1];  // [4096,64]
    float* out = (float*)d_out;              // [0]=cost, [1..N*N]=pi, [1+N*N..]=C
    float* C = out + 1 + (size_t)N * N;
    float* Ct = out;  // scratch: aliases cost+pi region, dead before final writes
    float* ws = (float*)d_ws;

    init_ws<<<dim3((WS_TOTAL + 255) / 256), dim3(256), 0, stream>>>(ws);

    dim3 bgrid(64, 64);
    build_dist<<<bgrid, dim3(256), 0, stream>>>(x, y, C);   // C[i][j]
    build_dist<<<bgrid, dim3(256), 0, stream>>>(y, x, Ct);  // C^T[j][i]

    float target = EPS * logf(1.0f / (float)N + 1e-8f);  // == eps*log_mu == eps*log_nu

    sinkhorn_persist<<<dim3(NBLK), dim3(TPB), 0, stream>>>(C, Ct, ws, out, target);
}